// Round 4
// baseline (273.937 us; speedup 1.0000x reference)
//
#include <hip/hip_runtime.h>

typedef __bf16 bf16;
typedef bf16 bf16x8 __attribute__((ext_vector_type(8)));
typedef float f32x4 __attribute__((ext_vector_type(4)));
typedef unsigned short ushort;
typedef ushort ushort4v __attribute__((ext_vector_type(4)));

#define BB 8192   // batch
#define NN 2048   // nodes

// ---------------------------------------------------------------------------
__device__ __forceinline__ void async16(const void* g, void* l) {
    __builtin_amdgcn_global_load_lds(
        (__attribute__((address_space(1))) void*)(void*)g,
        (__attribute__((address_space(3))) void*)l,
        16, 0, 0);
}

// ---------------------------------------------------------------------------
// K1 v4: gather-conv, 4 batch rows/block, nodes packed (x0,l0,x1,l1,x2,l2,
// x3,l3) bf16 in one 16B entry -> ONE ds_read_b128 per node serves FOUR rows
// (halves random-gather LDS traffic per output vs the 2-row f32 pack).
// Entry index XOR-swizzled (n ^= (n>>3)&7) so staging writes spread across
// all 8 bank-quads. bf16 conv inputs: error budget ~0.005 into y, amplified
// ~0.002-0.006 through the GEMM; threshold 2.64e-2 has ~2x margin.
__global__ __launch_bounds__(256) void conv_gather(
    const float* __restrict__ x, const float* __restrict__ label,
    const int* __restrict__ adj, const float* __restrict__ cw,
    const float* __restrict__ cb, bf16* __restrict__ V) {
    __shared__ bf16x8 sxl[NN];   // 32 KB
    const int bb0 = blockIdx.x * 4;
    const int t   = threadIdx.x;

    const float4* x0 = (const float4*)(x     + (size_t)(bb0 + 0) * NN);
    const float4* x1 = (const float4*)(x     + (size_t)(bb0 + 1) * NN);
    const float4* x2 = (const float4*)(x     + (size_t)(bb0 + 2) * NN);
    const float4* x3 = (const float4*)(x     + (size_t)(bb0 + 3) * NN);
    const float4* l0 = (const float4*)(label + (size_t)(bb0 + 0) * NN);
    const float4* l1 = (const float4*)(label + (size_t)(bb0 + 1) * NN);
    const float4* l2 = (const float4*)(label + (size_t)(bb0 + 2) * NN);
    const float4* l3 = (const float4*)(label + (size_t)(bb0 + 3) * NN);

#pragma unroll
    for (int q = 0; q < 2; ++q) {
        int i = q * 256 + t;             // float4 index, 512 per row
        float4 xa = x0[i], xb = x1[i], xc = x2[i], xd = x3[i];
        float4 la = l0[i], lb2 = l1[i], lc = l2[i], ld2 = l3[i];
        int n0i = i * 4;
        int sx  = (i >> 1) & 7;          // == ((n0i+j)>>3)&7 for j=0..3
        bf16x8 e;
        e[0]=(bf16)xa.x; e[1]=(bf16)la.x;  e[2]=(bf16)xb.x; e[3]=(bf16)lb2.x;
        e[4]=(bf16)xc.x; e[5]=(bf16)lc.x;  e[6]=(bf16)xd.x; e[7]=(bf16)ld2.x;
        sxl[(n0i + 0) ^ sx] = e;
        e[0]=(bf16)xa.y; e[1]=(bf16)la.y;  e[2]=(bf16)xb.y; e[3]=(bf16)lb2.y;
        e[4]=(bf16)xc.y; e[5]=(bf16)lc.y;  e[6]=(bf16)xd.y; e[7]=(bf16)ld2.y;
        sxl[(n0i + 1) ^ sx] = e;
        e[0]=(bf16)xa.z; e[1]=(bf16)la.z;  e[2]=(bf16)xb.z; e[3]=(bf16)lb2.z;
        e[4]=(bf16)xc.z; e[5]=(bf16)lc.z;  e[6]=(bf16)xd.z; e[7]=(bf16)ld2.z;
        sxl[(n0i + 2) ^ sx] = e;
        e[0]=(bf16)xa.w; e[1]=(bf16)la.w;  e[2]=(bf16)xb.w; e[3]=(bf16)lb2.w;
        e[4]=(bf16)xc.w; e[5]=(bf16)lc.w;  e[6]=(bf16)xd.w; e[7]=(bf16)ld2.w;
        sxl[(n0i + 3) ^ sx] = e;
    }
    const float w0 = cw[0], w1 = cw[1], w2 = cw[2], w3 = cw[3];
    const float w4 = cw[4], w5 = cw[5], w6 = cw[6], w7 = cw[7];
    const float bias = cb[0];

    const int4* adj4 = (const int4*)adj;
    int4 a[8];
#pragma unroll
    for (int j = 0; j < 8; ++j) a[j] = adj4[t * 8 + j];

    __syncthreads();

    bf16 o0[8], o1[8], o2[8], o3[8];
#pragma unroll
    for (int j = 0; j < 8; ++j) {
        int4 aa = a[j];
        bf16x8 p0 = sxl[aa.x ^ ((aa.x >> 3) & 7)];
        bf16x8 p1 = sxl[aa.y ^ ((aa.y >> 3) & 7)];
        bf16x8 p2 = sxl[aa.z ^ ((aa.z >> 3) & 7)];
        bf16x8 p3 = sxl[aa.w ^ ((aa.w >> 3) & 7)];
        float v0 = bias
                 + w0*(float)p0[0] + w1*(float)p1[0] + w2*(float)p2[0] + w3*(float)p3[0]
                 + w4*(float)p0[1] + w5*(float)p1[1] + w6*(float)p2[1] + w7*(float)p3[1];
        float v1 = bias
                 + w0*(float)p0[2] + w1*(float)p1[2] + w2*(float)p2[2] + w3*(float)p3[2]
                 + w4*(float)p0[3] + w5*(float)p1[3] + w6*(float)p2[3] + w7*(float)p3[3];
        float v2 = bias
                 + w0*(float)p0[4] + w1*(float)p1[4] + w2*(float)p2[4] + w3*(float)p3[4]
                 + w4*(float)p0[5] + w5*(float)p1[5] + w6*(float)p2[5] + w7*(float)p3[5];
        float v3 = bias
                 + w0*(float)p0[6] + w1*(float)p1[6] + w2*(float)p2[6] + w3*(float)p3[6]
                 + w4*(float)p0[7] + w5*(float)p1[7] + w6*(float)p2[7] + w7*(float)p3[7];
        o0[j] = (bf16)fmaxf(v0, 0.0f);
        o1[j] = (bf16)fmaxf(v1, 0.0f);
        o2[j] = (bf16)fmaxf(v2, 0.0f);
        o3[j] = (bf16)fmaxf(v3, 0.0f);
    }
    *(bf16x8*)(V + (size_t)(bb0 + 0) * NN + t * 8) = *(const bf16x8*)o0;
    *(bf16x8*)(V + (size_t)(bb0 + 1) * NN + t * 8) = *(const bf16x8*)o1;
    *(bf16x8*)(V + (size_t)(bb0 + 2) * NN + t * 8) = *(const bf16x8*)o2;
    *(bf16x8*)(V + (size_t)(bb0 + 3) * NN + t * 8) = *(const bf16x8*)o3;
}

// ---------------------------------------------------------------------------
// K2: fused (a) transpose V (8192x2048 bf16) -> Y2 (2048x8192), blocks 0..4095
//           (b) lin_w f32 -> bf16 (4.19M floats),               blocks 4096..6143
__global__ __launch_bounds__(256) void transp_cvtw(
    const ushort* __restrict__ V, ushort* __restrict__ Y,
    const float* __restrict__ W, bf16* __restrict__ Wb) {
    const int b = blockIdx.x;
    if (b >= 4096) {
        size_t i = (size_t)(b - 4096) * 256 + threadIdx.x;
        float4 v0 = ((const float4*)W)[i * 2 + 0];
        float4 v1 = ((const float4*)W)[i * 2 + 1];
        bf16x8 o;
        o[0] = (bf16)v0.x; o[1] = (bf16)v0.y; o[2] = (bf16)v0.z; o[3] = (bf16)v0.w;
        o[4] = (bf16)v1.x; o[5] = (bf16)v1.y; o[6] = (bf16)v1.z; o[7] = (bf16)v1.w;
        ((bf16x8*)Wb)[i] = o;
        return;
    }
    __shared__ __attribute__((aligned(16))) ushort tile[64][68];
    const int g0 = (b & 31) * 64;    // V col / Y row
    const int p0 = (b >> 5) * 64;    // V row / Y col
    const int c  = threadIdx.x & 15;
    const int r4 = threadIdx.x >> 4;   // [0,16)

#pragma unroll
    for (int pass = 0; pass < 4; ++pass) {
        int r = pass * 16 + r4;
        ushort4v v = *(const ushort4v*)(V + (size_t)(p0 + r) * NN + g0 + c * 4);
        *(ushort4v*)&tile[r][c * 4] = v;
    }
    __syncthreads();
    ushort4v rv[4];
#pragma unroll
    for (int j = 0; j < 4; ++j)
        rv[j] = *(const ushort4v*)&tile[c * 4 + j][r4 * 4];
#pragma unroll
    for (int q = 0; q < 4; ++q) {
        ushort4v o;
        o.x = rv[0][q]; o.y = rv[1][q]; o.z = rv[2][q]; o.w = rv[3][q];
        *(ushort4v*)(Y + (size_t)(g0 + r4 * 4 + q) * BB + p0 + c * 4) = o;
    }
}

// ---------------------------------------------------------------------------
// K3: out(8192x2048) = A * W^T + bias.  256x256 tile, BK=64, 8 waves, 512 thr.
// R4 changes vs R3 (same stage placement + vmcnt(6) ledger, verified in R3):
//  * ONE barrier per phase (post-MM) instead of two. Hazard proof:
//    - STG(phase p+1, DMA->buffer X) vs ds_reads of X (phase p): STG issues
//      after BAR_p; every wave reaches BAR_p only after its lgkm-drain+MM_p,
//      so all reads of X are already in registers.  [BAR1 was redundant]
//    - buffer-ready: VMW6 sits BEFORE the ph4/ph8 barrier, so after that
//      barrier every wave's pieces of the next buffer have landed.
//    Fast waves now slip into the next phase's ds_reads/STG while slow waves
//    are still in MFMA -> cross-wave LDS/MFMA overlap the old lockstep forbade.
//  * Within-wave split: each read-phase = group1 reads, group2 reads, STG,
//    lgkmcnt(4|2) -> 8 MFMA -> lgkmcnt(0) -> 8 MFMA (counted waits; the
//    compiler's own dep-waits keep this correct under any reordering).
//  * Epilogue re-staged through per-wave LDS (16x68 f32, conflict-free) ->
//    fully coalesced dwordx4 stores (was scattered 4B/lane).
__global__ __launch_bounds__(512, 2) void gemm_bt(
    const bf16* __restrict__ A, const bf16* __restrict__ W,
    const float* __restrict__ bias, float* __restrict__ out) {
    __shared__ __attribute__((aligned(16))) bf16 sA[2][16384];
    __shared__ __attribute__((aligned(16))) bf16 sB[2][16384];

    const int t    = threadIdx.x;
    const int lane = t & 63;
    const int wv   = t >> 6;
    const int wm   = wv & 1;     // 2 M-waves
    const int wn   = wv >> 1;    // 4 N-waves
    const int l16  = lane & 15;
    const int l4   = lane >> 4;

    // Chunked XCD mapping: each XCD owns 4 bx (A panels) x all 8 by.
    const int xcd = blockIdx.x & 7;
    const int loc = blockIdx.x >> 3;        // [0,32)
    const int bx  = xcd * 4 + (loc >> 3);   // [0,32)
    const int by  = loc & 7;                // [0,8)
    const int m0  = bx * 256;
    const int n0  = by * 256;

    const int r8  = t >> 3;
    const int c8  = ((t & 7) ^ (r8 & 7)) * 8;
    const int dst = t * 8;

    const int sw    = l16 & 7;
    const int aOff0 = (wm * 128 + l16) * 64 + ((l4    ) ^ sw) * 8;
    const int aOff1 = (wm * 128 + l16) * 64 + ((l4 + 4) ^ sw) * 8;
    const int bOff0 = (wn * 64  + l16) * 64 + ((l4    ) ^ sw) * 8;
    const int bOff1 = (wn * 64  + l16) * 64 + ((l4 + 4) ^ sw) * 8;

    f32x4  acc[8][4] = {};
    bf16x8 aR[4][2], bR[4][2];

#define GBAR()   asm volatile("s_barrier" ::: "memory")
#define LGKM(N)  do { asm volatile("s_waitcnt lgkmcnt(" #N ")" ::: "memory"); \
                      __builtin_amdgcn_sched_barrier(0); } while (0)
#define LGKMP(N) do { __builtin_amdgcn_sched_barrier(0);                      \
                      asm volatile("s_waitcnt lgkmcnt(" #N ")" ::: "memory"); \
                      __builtin_amdgcn_sched_barrier(0); } while (0)
#define VMW6()   asm volatile("s_waitcnt vmcnt(6)" ::: "memory")
#define VMW0()   asm volatile("s_waitcnt vmcnt(0)" ::: "memory")

#define STG(G, rb, kt, lp) do {                                           \
        const bf16* _s = (G) + (size_t)((rb) + r8) * 2048 + (kt) + c8;    \
        async16(_s, (lp) + dst);                                          \
        async16(_s + (size_t)64 * 2048, (lp) + 4096 + dst);               \
    } while (0)

// aR pair group: g=0 -> aR0,aR1 ; g=1 -> aR2,aR3   (4 ds_read_b128 each)
#define LDA2(sp, mh, g) do {                                              \
        const bf16* _p = (sp) + (mh) * 4096 + (g) * 2048;                 \
        aR[(g)*2+0][0] = *(const bf16x8*)(_p + aOff0);                    \
        aR[(g)*2+0][1] = *(const bf16x8*)(_p + aOff1);                    \
        aR[(g)*2+1][0] = *(const bf16x8*)(_p + 1024 + aOff0);             \
        aR[(g)*2+1][1] = *(const bf16x8*)(_p + 1024 + aOff1);             \
    } while (0)

// one bR fragment (2 ds_read_b128): nfA in [0,4)
#define LDB1(sp, nfA) do {                                                \
        const bf16* _p = (sp) + ((nfA) >> 1) * 2048 + ((nfA) & 1) * 1024; \
        bR[nfA][0] = *(const bf16x8*)(_p + bOff0);                        \
        bR[nfA][1] = *(const bf16x8*)(_p + bOff1);                        \
    } while (0)

// 8 MFMAs: mf in {2h, 2h+1} x nf {nh*2, nh*2+1} x ks {0,1}
#define MM8_MF(mh, nh, h)                                                 \
    _Pragma("unroll")                                                     \
    for (int _ks = 0; _ks < 2; ++_ks)                                     \
        _Pragma("unroll")                                                 \
        for (int _mf = (h)*2; _mf < (h)*2+2; ++_mf)                       \
            _Pragma("unroll")                                             \
            for (int _nf = 0; _nf < 2; ++_nf)                             \
                acc[(mh)*4+_mf][(nh)*2+_nf] =                             \
                    __builtin_amdgcn_mfma_f32_16x16x32_bf16(              \
                        aR[_mf][_ks], bR[(nh)*2+_nf][_ks],                \
                        acc[(mh)*4+_mf][(nh)*2+_nf], 0, 0, 0)

// 8 MFMAs: all mf 0..3, single absolute nfA, ks {0,1}
#define MM8_NF(mh, nfA)                                                   \
    _Pragma("unroll")                                                     \
    for (int _ks = 0; _ks < 2; ++_ks)                                     \
        _Pragma("unroll")                                                 \
        for (int _mf = 0; _mf < 4; ++_mf)                                 \
            acc[(mh)*4+_mf][nfA] =                                        \
                __builtin_amdgcn_mfma_f32_16x16x32_bf16(                  \
                    aR[_mf][_ks], bR[nfA][_ks],                           \
                    acc[(mh)*4+_mf][nfA], 0, 0, 0)

#define PRIO1() __builtin_amdgcn_s_setprio(1)
#define PRIO0() __builtin_amdgcn_s_setprio(0)

    bf16* const sA0 = &sA[0][0]; bf16* const sA1 = &sA[1][0];
    bf16* const sB0 = &sB[0][0]; bf16* const sB1 = &sB[1][0];

    // prologue: A(0),B(0) (8 ops) + B(1),A(1).h0 (6 ops) = 14; vmcnt(6)
    // retires the 8 oldest = all of tile 0, leaving the steady-state
    // invariant {B(1).h0, B(1).h1, A(1).h0}.
    STG(A, m0,       0,  sA0);
    STG(A, m0 + 128, 0,  sA0 + 8192);
    STG(W, n0,       0,  sB0);
    STG(W, n0 + 128, 0,  sB0 + 8192);
    STG(W, n0,       64, sB1);
    STG(W, n0 + 128, 64, sB1 + 8192);
    STG(A, m0,       64, sA1);
    VMW6();
    GBAR();

    for (int i = 0; i < 15; ++i) {
        const int kb = i * 128;
        // ph1: buf0 Q(0,0); stage A(2i+1).h1
        LDB1(sB0, 0); LDB1(sB0, 1); LDA2(sA0, 0, 0);   // 8 reads
        LDA2(sA0, 0, 1);                               // +4
        STG(A, m0 + 128, kb + 64, sA1 + 8192);
        LGKM(4);  PRIO1(); MM8_MF(0, 0, 0);
        LGKMP(0);          MM8_MF(0, 0, 1); PRIO0();
        GBAR();
        // ph2: Q(0,1)
        LDB1(sB0, 2);                                  // 2 reads
        LDB1(sB0, 3);                                  // +2
        LGKM(2);  PRIO1(); MM8_NF(0, 2);
        LGKMP(0);          MM8_NF(0, 3); PRIO0();
        GBAR();
        // ph3: Q(1,0); stage B(2i+2).h0 (sB0.h0 dead after ph2's barrier)
        LDA2(sA0, 1, 0);                               // 4 reads
        LDA2(sA0, 1, 1);                               // +4
        STG(W, n0, kb + 128, sB0);
        LGKM(4);  PRIO1(); MM8_MF(1, 0, 0);
        LGKMP(0);          MM8_MF(1, 0, 1); PRIO0();
        GBAR();
        // ph4: Q(1,1) (no reads); stage B(2i+2).h1 + A(2i+2).h0; wait buf1
        STG(W, n0 + 128, kb + 128, sB0 + 8192);
        STG(A, m0,       kb + 128, sA0);
        PRIO1(); MM8_NF(1, 2); MM8_NF(1, 3); PRIO0();
        VMW6();
        GBAR();
        // ph5: buf1 Q(0,0); stage A(2i+2).h1
        LDB1(sB1, 0); LDB1(sB1, 1); LDA2(sA1, 0, 0);
        LDA2(sA1, 0, 1);
        STG(A, m0 + 128, kb + 128, sA0 + 8192);
        LGKM(4);  PRIO1(); MM8_MF(0, 0, 0);
        LGKMP(0);          MM8_MF(0, 0, 1); PRIO0();
        GBAR();
        // ph6
        LDB1(sB1, 2);
        LDB1(sB1, 3);
        LGKM(2);  PRIO1(); MM8_NF(0, 2);
        LGKMP(0);          MM8_NF(0, 3); PRIO0();
        GBAR();
        // ph7: stage B(2i+3).h0
        LDA2(sA1, 1, 0);
        LDA2(sA1, 1, 1);
        STG(W, n0, kb + 192, sB1);
        LGKM(4);  PRIO1(); MM8_MF(1, 0, 0);
        LGKMP(0);          MM8_MF(1, 0, 1); PRIO0();
        GBAR();
        // ph8: stage B(2i+3).h1 + A(2i+3).h0; wait buf0
        STG(W, n0 + 128, kb + 192, sB1 + 8192);
        STG(A, m0,       kb + 192, sA1);
        PRIO1(); MM8_NF(1, 2); MM8_NF(1, 3); PRIO0();
        VMW6();
        GBAR();
    }

    // tail: tiles 30 (buf0) / 31 (buf1); only A(31).h1 remains to stage
    LDB1(sB0, 0); LDB1(sB0, 1); LDA2(sA0, 0, 0);
    LDA2(sA0, 0, 1);
    STG(A, m0 + 128, 1984, sA1 + 8192);
    LGKM(4);  PRIO1(); MM8_MF(0, 0, 0);
    LGKMP(0);          MM8_MF(0, 0, 1); PRIO0();
    GBAR();
    LDB1(sB0, 2); LDB1(sB0, 3);
    LGKM(2);  PRIO1(); MM8_NF(0, 2);
    LGKMP(0);          MM8_NF(0, 3); PRIO0();
    GBAR();
    LDA2(sA0, 1, 0); LDA2(sA0, 1, 1);
    LGKM(4);  PRIO1(); MM8_MF(1, 0, 0);
    LGKMP(0);          MM8_MF(1, 0, 1); PRIO0();
    GBAR();
    PRIO1(); MM8_NF(1, 2); MM8_NF(1, 3); PRIO0();
    VMW0();                      // drain tile 31 completely
    GBAR();
    LDB1(sB1, 0); LDB1(sB1, 1); LDA2(sA1, 0, 0);
    LDA2(sA1, 0, 1);
    LGKM(4);  PRIO1(); MM8_MF(0, 0, 0);
    LGKMP(0);          MM8_MF(0, 0, 1); PRIO0();
    GBAR();
    LDB1(sB1, 2); LDB1(sB1, 3);
    LGKM(2);  PRIO1(); MM8_NF(0, 2);
    LGKMP(0);          MM8_NF(0, 3); PRIO0();
    GBAR();
    LDA2(sA1, 1, 0); LDA2(sA1, 1, 1);
    LGKM(4);  PRIO1(); MM8_MF(1, 0, 0);
    LGKMP(0);          MM8_MF(1, 0, 1); PRIO0();
    GBAR();
    PRIO1(); MM8_NF(1, 2); MM8_NF(1, 3); PRIO0();

    // all LDS dead after this barrier -> reuse for epilogue staging
    GBAR();

    // epilogue: per-wave 16x68 f32 LDS re-stage -> coalesced dwordx4 stores
    {
        float* ep = (float*)&sA[0][0] + wv * (16 * 68);   // 4352 B/wave
        const int cb0 = n0 + wn * 64;
        float bc[4];
#pragma unroll
        for (int nf = 0; nf < 4; ++nf) bc[nf] = bias[cb0 + nf * 16 + l16];
        const int rw = lane >> 2;      // [0,16) read row
        const int cg = lane & 3;       // [0,4)  16-col group
#pragma unroll
        for (int mf = 0; mf < 8; ++mf) {
#pragma unroll
            for (int nf = 0; nf < 4; ++nf)
#pragma unroll
                for (int rr = 0; rr < 4; ++rr)
                    ep[(l4 * 4 + rr) * 68 + nf * 16 + l16] =
                        acc[mf][nf][rr] + bc[nf];
            asm volatile("s_waitcnt lgkmcnt(0)" ::: "memory");
            const size_t rowb = (size_t)(m0 + wm * 128 + mf * 16 + rw);
            float* op = out + rowb * 2048 + cb0 + cg * 16;
            const float* rp = ep + rw * 68 + cg * 16;
            f32x4 v0 = *(const f32x4*)(rp + 0);
            f32x4 v1 = *(const f32x4*)(rp + 4);
            f32x4 v2 = *(const f32x4*)(rp + 8);
            f32x4 v3 = *(const f32x4*)(rp + 12);
            asm volatile("s_waitcnt lgkmcnt(0)" ::: "memory");
            *(f32x4*)(op + 0)  = v0;
            *(f32x4*)(op + 4)  = v1;
            *(f32x4*)(op + 8)  = v2;
            *(f32x4*)(op + 12) = v3;
        }
    }
#undef STG
#undef LDA2
#undef LDB1
#undef MM8_MF
#undef MM8_NF
#undef GBAR
#undef LGKM
#undef LGKMP
#undef VMW6
#undef VMW0
#undef PRIO1
#undef PRIO0
}

// ---------------------------------------------------------------------------
extern "C" void kernel_launch(void* const* d_in, const int* in_sizes, int n_in,
                              void* d_out, int out_size, void* d_ws, size_t ws_size,
                              hipStream_t stream) {
    (void)in_sizes; (void)n_in; (void)out_size; (void)ws_size;
    const float* x     = (const float*)d_in[0];
    const float* label = (const float*)d_in[1];
    const int*   adj   = (const int*)d_in[2];
    const float* cw    = (const float*)d_in[3];
    const float* cb    = (const float*)d_in[4];
    const float* lw    = (const float*)d_in[5];
    const float* lb    = (const float*)d_in[6];
    float* out = (float*)d_out;

    // scratch: V (32MB) in d_out (overwritten by GEMM), Y2 at ws, Wb at ws+32MB
    bf16* V  = (bf16*)d_out;
    bf16* Y2 = (bf16*)d_ws;
    bf16* Wb = (bf16*)((char*)d_ws + (size_t)2048 * 8192 * 2);

    conv_gather<<<BB / 4, 256, 0, stream>>>(x, label, adj, cw, cb, V);
    transp_cvtw<<<6144, 256, 0, stream>>>((const ushort*)V, (ushort*)Y2,
                                          lw, Wb);
    gemm_bt<<<dim3(256), 512, 0, stream>>>(Y2, Wb, lb, out);
}

// Round 6
// 267.189 us; speedup vs baseline: 1.0253x; 1.0253x over previous
//
#include <hip/hip_runtime.h>

typedef __bf16 bf16;
typedef bf16 bf16x8 __attribute__((ext_vector_type(8)));
typedef float f32x4 __attribute__((ext_vector_type(4)));
typedef unsigned short ushort;
typedef ushort ushort4v __attribute__((ext_vector_type(4)));

#define BB 8192   // batch
#define NN 2048   // nodes

// ---------------------------------------------------------------------------
__device__ __forceinline__ void async16(const void* g, void* l) {
    __builtin_amdgcn_global_load_lds(
        (__attribute__((address_space(1))) void*)(void*)g,
        (__attribute__((address_space(3))) void*)l,
        16, 0, 0);
}

// ---------------------------------------------------------------------------
// K1 v5: gather-conv writing the TRANSPOSED batch-8-grouped layout
//   V'[g][p][e] = conv(batch g*8+e, node p),  g in [0,1024), p in [0,2048), e in [0,8)
// which makes gemm's A-operand 16B-contiguous:
//   A[m][k0..k0+8) = V'[(m&3)*256 + k0/8][m>>2][0..8)
// -> the separate V->Y2 transpose kernel (K2) is ELIMINATED (saves 67 MB HBM
// round-trip + one dispatch).
// Block = 8 batch rows, two 4-row passes sharing one 32KB LDS stage (nodes
// packed (x0,l0,..,x3,l3) bf16 in 16B -> ONE ds_read_b128 per node serves 4
// rows). Per-block output V'[g][*][*] = 32KB CONTIGUOUS; thread t owns bytes
// t*128..t*128+128 -> fully coalesced stores, no LDS re-stage needed.
// Blocks >= 1024 do the lin_w f32->bf16 convert (folded-in, overlaps K1 tail).
__global__ __launch_bounds__(256) void conv_gather_t(
    const float* __restrict__ x, const float* __restrict__ label,
    const int* __restrict__ adj, const float* __restrict__ cw,
    const float* __restrict__ cb, bf16* __restrict__ Vp,
    const float* __restrict__ W, bf16* __restrict__ Wb) {
    const int blk = blockIdx.x;
    const int t   = threadIdx.x;

    if (blk >= 1024) {
        // lin_w convert: 1024 blocks x 256 thr x 16 floats = 4.19M floats
        const size_t f4 = ((size_t)(blk - 1024) * 256 + t) * 4;
        const float4* Wf = (const float4*)W;
        float4 v0 = Wf[f4 + 0], v1 = Wf[f4 + 1];
        float4 v2 = Wf[f4 + 2], v3 = Wf[f4 + 3];
        bf16x8 o0, o1;
        o0[0]=(bf16)v0.x; o0[1]=(bf16)v0.y; o0[2]=(bf16)v0.z; o0[3]=(bf16)v0.w;
        o0[4]=(bf16)v1.x; o0[5]=(bf16)v1.y; o0[6]=(bf16)v1.z; o0[7]=(bf16)v1.w;
        o1[0]=(bf16)v2.x; o1[1]=(bf16)v2.y; o1[2]=(bf16)v2.z; o1[3]=(bf16)v2.w;
        o1[4]=(bf16)v3.x; o1[5]=(bf16)v3.y; o1[6]=(bf16)v3.z; o1[7]=(bf16)v3.w;
        ((bf16x8*)Wb)[(f4 >> 1) + 0] = o0;
        ((bf16x8*)Wb)[(f4 >> 1) + 1] = o1;
        return;
    }

    __shared__ bf16x8 sxl[NN];   // 32 KB
    const int bb0 = blk * 8;

    const float w0 = cw[0], w1 = cw[1], w2 = cw[2], w3 = cw[3];
    const float w4 = cw[4], w5 = cw[5], w6 = cw[6], w7 = cw[7];
    const float bias = cb[0];

    const int4* adj4 = (const int4*)adj;
    int4 a[8];
#pragma unroll
    for (int j = 0; j < 8; ++j) a[j] = adj4[t * 8 + j];

    bf16 oA[8][4], oB[8][4];

#pragma unroll
    for (int pp = 0; pp < 2; ++pp) {
        if (pp) __syncthreads();   // protect pass-0 reads from restage
        const int rb = bb0 + pp * 4;
        const float4* x0 = (const float4*)(x     + (size_t)(rb + 0) * NN);
        const float4* x1 = (const float4*)(x     + (size_t)(rb + 1) * NN);
        const float4* x2 = (const float4*)(x     + (size_t)(rb + 2) * NN);
        const float4* x3 = (const float4*)(x     + (size_t)(rb + 3) * NN);
        const float4* l0 = (const float4*)(label + (size_t)(rb + 0) * NN);
        const float4* l1 = (const float4*)(label + (size_t)(rb + 1) * NN);
        const float4* l2 = (const float4*)(label + (size_t)(rb + 2) * NN);
        const float4* l3 = (const float4*)(label + (size_t)(rb + 3) * NN);
#pragma unroll
        for (int q = 0; q < 2; ++q) {
            int i = q * 256 + t;             // float4 index, 512 per row
            float4 xa = x0[i], xb = x1[i], xc = x2[i], xd = x3[i];
            float4 la = l0[i], lb = l1[i], lc = l2[i], ld = l3[i];
            int n0i = i * 4;
            int sx  = (i >> 1) & 7;          // == ((n0i+c)>>3)&7 for c=0..3
            bf16x8 e;
            e[0]=(bf16)xa.x; e[1]=(bf16)la.x; e[2]=(bf16)xb.x; e[3]=(bf16)lb.x;
            e[4]=(bf16)xc.x; e[5]=(bf16)lc.x; e[6]=(bf16)xd.x; e[7]=(bf16)ld.x;
            sxl[(n0i + 0) ^ sx] = e;
            e[0]=(bf16)xa.y; e[1]=(bf16)la.y; e[2]=(bf16)xb.y; e[3]=(bf16)lb.y;
            e[4]=(bf16)xc.y; e[5]=(bf16)lc.y; e[6]=(bf16)xd.y; e[7]=(bf16)ld.y;
            sxl[(n0i + 1) ^ sx] = e;
            e[0]=(bf16)xa.z; e[1]=(bf16)la.z; e[2]=(bf16)xb.z; e[3]=(bf16)lb.z;
            e[4]=(bf16)xc.z; e[5]=(bf16)lc.z; e[6]=(bf16)xd.z; e[7]=(bf16)ld.z;
            sxl[(n0i + 2) ^ sx] = e;
            e[0]=(bf16)xa.w; e[1]=(bf16)la.w; e[2]=(bf16)xb.w; e[3]=(bf16)lb.w;
            e[4]=(bf16)xc.w; e[5]=(bf16)lc.w; e[6]=(bf16)xd.w; e[7]=(bf16)ld.w;
            sxl[(n0i + 3) ^ sx] = e;
        }
        __syncthreads();

        bf16 (*od)[4] = pp ? oB : oA;
#pragma unroll
        for (int j = 0; j < 8; ++j) {
            int4 aa = a[j];
            bf16x8 p0 = sxl[aa.x ^ ((aa.x >> 3) & 7)];
            bf16x8 p1 = sxl[aa.y ^ ((aa.y >> 3) & 7)];
            bf16x8 p2 = sxl[aa.z ^ ((aa.z >> 3) & 7)];
            bf16x8 p3 = sxl[aa.w ^ ((aa.w >> 3) & 7)];
            float v0 = bias
                + w0*(float)p0[0] + w1*(float)p1[0] + w2*(float)p2[0] + w3*(float)p3[0]
                + w4*(float)p0[1] + w5*(float)p1[1] + w6*(float)p2[1] + w7*(float)p3[1];
            float v1 = bias
                + w0*(float)p0[2] + w1*(float)p1[2] + w2*(float)p2[2] + w3*(float)p3[2]
                + w4*(float)p0[3] + w5*(float)p1[3] + w6*(float)p2[3] + w7*(float)p3[3];
            float v2 = bias
                + w0*(float)p0[4] + w1*(float)p1[4] + w2*(float)p2[4] + w3*(float)p3[4]
                + w4*(float)p0[5] + w5*(float)p1[5] + w6*(float)p2[5] + w7*(float)p3[5];
            float v3 = bias
                + w0*(float)p0[6] + w1*(float)p1[6] + w2*(float)p2[6] + w3*(float)p3[6]
                + w4*(float)p0[7] + w5*(float)p1[7] + w6*(float)p2[7] + w7*(float)p3[7];
            od[j][0] = (bf16)fmaxf(v0, 0.0f);
            od[j][1] = (bf16)fmaxf(v1, 0.0f);
            od[j][2] = (bf16)fmaxf(v2, 0.0f);
            od[j][3] = (bf16)fmaxf(v3, 0.0f);
        }
    }

    // coalesced V' store: block slab = 32KB contiguous; thread t owns
    // bytes t*128 .. t*128+128 (nodes t*8..t*8+7, all 8 batches each).
    bf16* vout = Vp + (size_t)blk * 16384 + t * 64;
#pragma unroll
    for (int j = 0; j < 8; ++j) {
        bf16x8 e;
        e[0] = oA[j][0]; e[1] = oA[j][1]; e[2] = oA[j][2]; e[3] = oA[j][3];
        e[4] = oB[j][0]; e[5] = oB[j][1]; e[6] = oB[j][2]; e[7] = oB[j][3];
        *(bf16x8*)(vout + j * 8) = e;
    }
}

// ---------------------------------------------------------------------------
// K3: out(8192x2048) = A * W^T + bias.  EXACT R3 schedule (measured 72.6 us,
// MfmaUtil 37, 0 bank conflicts) -- only the A-staging SOURCE address changed
// to read the V' layout:
//   srcA(m, kk) = Vp + ((m&3)*256 + kk/8)*16384 + (m>>2)*8      [kk%8==0]
// (verified: == old Y2-flat[m*2048+kk]; second half-row m+64 is +128 elems).
// 256x256 tile, BK=64, 8 waves (2Mx4N), 512 threads, 128 KiB LDS.
// Stage plan (iter i, buf0 = tile 2i, buf1 = tile 2i+1):
//   ph1: A(2i+1).h1->sA1   ph3: B(2i+2).h0->sB0
//   ph4: B(2i+2).h1->sB0, A(2i+2).h0->sA0   [vmcnt(6): all of tile 2i+1 landed]
//   ph5: A(2i+2).h1->sA0   ph7: B(2i+3).h0->sB1
//   ph8: B(2i+3).h1->sB1, A(2i+3).h0->sA1   [vmcnt(6): all of tile 2i+2 landed]
// Ledger: enter iter with 6 outstanding {B.h0,B.h1,A.h0 of buf1-tile};
// ph1:8 -> ph3:10 -> ph4:14 wait(6) -> ph5:8 -> ph7:10 -> ph8:14 wait(6).
// Prologue issues A(0),B(0),B(1),A(1).h0 = 14 ops; vmcnt(6) retires tile 0.
__global__ __launch_bounds__(512, 2) void gemm_bt(
    const bf16* __restrict__ A, const bf16* __restrict__ W,
    const float* __restrict__ bias, float* __restrict__ out) {
    __shared__ __attribute__((aligned(16))) bf16 sA[2][16384];
    __shared__ __attribute__((aligned(16))) bf16 sB[2][16384];

    const int t    = threadIdx.x;
    const int lane = t & 63;
    const int wv   = t >> 6;
    const int wm   = wv & 1;     // 2 M-waves
    const int wn   = wv >> 1;    // 4 N-waves
    const int l16  = lane & 15;
    const int l4   = lane >> 4;

    // Chunked XCD mapping: each XCD owns 4 bx (A panels) x all 8 by.
    const int xcd = blockIdx.x & 7;
    const int loc = blockIdx.x >> 3;        // [0,32)
    const int bx  = xcd * 4 + (loc >> 3);   // [0,32)
    const int by  = loc & 7;                // [0,8)
    const int m0  = bx * 256;
    const int n0  = by * 256;

    const int r8  = t >> 3;
    const int c8  = ((t & 7) ^ (r8 & 7)) * 8;
    const int dst = t * 8;

    const int sw    = l16 & 7;
    const int aOff0 = (wm * 128 + l16) * 64 + ((l4    ) ^ sw) * 8;
    const int aOff1 = (wm * 128 + l16) * 64 + ((l4 + 4) ^ sw) * 8;
    const int bOff0 = (wn * 64  + l16) * 64 + ((l4    ) ^ sw) * 8;
    const int bOff1 = (wn * 64  + l16) * 64 + ((l4 + 4) ^ sw) * 8;

    f32x4  acc[8][4] = {};
    bf16x8 aR[4][2], bR[4][2];

#define GBAR()  asm volatile("s_barrier" ::: "memory")
#define LGKM0() do { asm volatile("s_waitcnt lgkmcnt(0)" ::: "memory"); \
                     __builtin_amdgcn_sched_barrier(0); } while (0)
#define VMW6()  asm volatile("s_waitcnt vmcnt(6)" ::: "memory")
#define VMW0()  asm volatile("s_waitcnt vmcnt(0)" ::: "memory")

// B (W) staging: row-major [n][k]
#define STGW(rb, kt, lp) do {                                             \
        const bf16* _s = W + (size_t)((rb) + r8) * 2048 + (kt) + c8;      \
        async16(_s, (lp) + dst);                                          \
        async16(_s + (size_t)64 * 2048, (lp) + 4096 + dst);               \
    } while (0)

// A staging from V': srcA(m,kk) = Vp + ((m&3)*256 + kk/8)*16384 + (m>>2)*8.
// Rows m and m+64 share (m&3) and kk -> second async16 source = first + 128.
#define STGA(rb, kt, lp) do {                                             \
        const int _m1 = (rb) + r8;                                        \
        const int _kk = (kt) + c8;                                        \
        const bf16* _s = A + ((size_t)(((_m1 & 3) << 8) + (_kk >> 3)) << 14) \
                           + ((_m1 >> 2) << 3);                           \
        async16(_s, (lp) + dst);                                          \
        async16(_s + 128, (lp) + 4096 + dst);                             \
    } while (0)

#define LDA(sp, mh) do {                                                  \
        const bf16* _p = (sp) + (mh) * 4096;                              \
        aR[0][0] = *(const bf16x8*)(_p + aOff0);                          \
        aR[0][1] = *(const bf16x8*)(_p + aOff1);                          \
        aR[1][0] = *(const bf16x8*)(_p + 1024 + aOff0);                   \
        aR[1][1] = *(const bf16x8*)(_p + 1024 + aOff1);                   \
        aR[2][0] = *(const bf16x8*)(_p + 2048 + aOff0);                   \
        aR[2][1] = *(const bf16x8*)(_p + 2048 + aOff1);                   \
        aR[3][0] = *(const bf16x8*)(_p + 3072 + aOff0);                   \
        aR[3][1] = *(const bf16x8*)(_p + 3072 + aOff1);                   \
    } while (0)

#define LDB(sp, nh) do {                                                  \
        const bf16* _p = (sp) + (nh) * 2048;                              \
        bR[(nh)*2+0][0] = *(const bf16x8*)(_p + bOff0);                   \
        bR[(nh)*2+0][1] = *(const bf16x8*)(_p + bOff1);                   \
        bR[(nh)*2+1][0] = *(const bf16x8*)(_p + 1024 + bOff0);            \
        bR[(nh)*2+1][1] = *(const bf16x8*)(_p + 1024 + bOff1);            \
    } while (0)

#define MM(mh, nh) do {                                                   \
        __builtin_amdgcn_s_setprio(1);                                    \
        _Pragma("unroll")                                                 \
        for (int _ks = 0; _ks < 2; ++_ks)                                 \
            _Pragma("unroll")                                             \
            for (int _mf = 0; _mf < 4; ++_mf)                             \
                _Pragma("unroll")                                         \
                for (int _nf = 0; _nf < 2; ++_nf)                         \
                    acc[(mh)*4+_mf][(nh)*2+_nf] =                         \
                        __builtin_amdgcn_mfma_f32_16x16x32_bf16(          \
                            aR[_mf][_ks], bR[(nh)*2+_nf][_ks],            \
                            acc[(mh)*4+_mf][(nh)*2+_nf], 0, 0, 0);        \
        __builtin_amdgcn_s_setprio(0);                                    \
    } while (0)

    bf16* const sA0 = &sA[0][0]; bf16* const sA1 = &sA[1][0];
    bf16* const sB0 = &sB[0][0]; bf16* const sB1 = &sB[1][0];

    // prologue: A(0),B(0) (8 ops) + B(1),A(1).h0 (6 ops) = 14; vmcnt(6)
    // retires the 8 oldest = all of tile 0, leaving invariant
    // {B(1).h0, B(1).h1, A(1).h0}.
    STGA(m0,       0,  sA0);
    STGA(m0 + 128, 0,  sA0 + 8192);
    STGW(n0,       0,  sB0);
    STGW(n0 + 128, 0,  sB0 + 8192);
    STGW(n0,       64, sB1);
    STGW(n0 + 128, 64, sB1 + 8192);
    STGA(m0,       64, sA1);
    VMW6();
    GBAR();

    for (int i = 0; i < 15; ++i) {
        const int kb = i * 128;
        // ph1: stage A(2i+1).h1
        LDA(sA0, 0); LDB(sB0, 0);
        STGA(m0 + 128, kb + 64, sA1 + 8192);
        GBAR(); LGKM0();
        MM(0, 0);
        GBAR();
        // ph2
        LDB(sB0, 1);
        GBAR(); LGKM0();
        MM(0, 1);
        GBAR();
        // ph3: stage B(2i+2).h0
        LDA(sA0, 1);
        STGW(n0, kb + 128, sB0);
        GBAR(); LGKM0();
        MM(1, 0);
        GBAR();
        // ph4: stage B(2i+2).h1 + A(2i+2).h0; wait buf1
        STGW(n0 + 128, kb + 128, sB0 + 8192);
        STGA(m0,       kb + 128, sA0);
        GBAR(); LGKM0();
        MM(1, 1);
        VMW6();
        GBAR();
        // ph5: stage A(2i+2).h1
        LDA(sA1, 0); LDB(sB1, 0);
        STGA(m0 + 128, kb + 128, sA0 + 8192);
        GBAR(); LGKM0();
        MM(0, 0);
        GBAR();
        // ph6
        LDB(sB1, 1);
        GBAR(); LGKM0();
        MM(0, 1);
        GBAR();
        // ph7: stage B(2i+3).h0
        LDA(sA1, 1);
        STGW(n0, kb + 192, sB1);
        GBAR(); LGKM0();
        MM(1, 0);
        GBAR();
        // ph8: stage B(2i+3).h1 + A(2i+3).h0; wait buf0
        STGW(n0 + 128, kb + 192, sB1 + 8192);
        STGA(m0,       kb + 192, sA1);
        GBAR(); LGKM0();
        MM(1, 1);
        VMW6();
        GBAR();
    }

    // tail: tiles 30 (buf0), 31 (buf1); only A(31).h1 remains to stage
    LDA(sA0, 0); LDB(sB0, 0);
    STGA(m0 + 128, 1984, sA1 + 8192);
    GBAR(); LGKM0(); MM(0, 0); GBAR();
    LDB(sB0, 1);
    GBAR(); LGKM0(); MM(0, 1); GBAR();
    LDA(sA0, 1);
    GBAR(); LGKM0(); MM(1, 0); GBAR();
    GBAR(); LGKM0(); MM(1, 1);
    VMW0();                      // drain tile 31
    GBAR();
    LDA(sA1, 0); LDB(sB1, 0);
    GBAR(); LGKM0(); MM(0, 0); GBAR();
    LDB(sB1, 1);
    GBAR(); LGKM0(); MM(0, 1); GBAR();
    LDA(sA1, 1);
    GBAR(); LGKM0(); MM(1, 0); GBAR();
    GBAR(); LGKM0(); MM(1, 1);

    // epilogue: bias + store (regs only)
#pragma unroll
    for (int nf = 0; nf < 4; ++nf) {
        const int col = n0 + wn * 64 + nf * 16 + l16;
        const float bc = bias[col];
#pragma unroll
        for (int mf = 0; mf < 8; ++mf) {
            const size_t row = (size_t)(m0 + wm * 128 + mf * 16 + l4 * 4);
#pragma unroll
            for (int rr = 0; rr < 4; ++rr)
                out[(row + rr) * 2048 + col] = acc[mf][nf][rr] + bc;
        }
    }
#undef STGW
#undef STGA
#undef LDA
#undef LDB
#undef MM
#undef GBAR
#undef LGKM0
#undef VMW6
#undef VMW0
}

// ---------------------------------------------------------------------------
extern "C" void kernel_launch(void* const* d_in, const int* in_sizes, int n_in,
                              void* d_out, int out_size, void* d_ws, size_t ws_size,
                              hipStream_t stream) {
    (void)in_sizes; (void)n_in; (void)out_size; (void)ws_size;
    const float* x     = (const float*)d_in[0];
    const float* label = (const float*)d_in[1];
    const int*   adj   = (const int*)d_in[2];
    const float* cw    = (const float*)d_in[3];
    const float* cb    = (const float*)d_in[4];
    const float* lw    = (const float*)d_in[5];
    const float* lb    = (const float*)d_in[6];
    float* out = (float*)d_out;

    // scratch: V' (33.5 MB) at ws, Wb at ws+33.5MB. No Y2, no V-in-d_out.
    bf16* Vp = (bf16*)d_ws;
    bf16* Wb = (bf16*)((char*)d_ws + (size_t)2048 * 8192 * 2);

    conv_gather_t<<<2048, 256, 0, stream>>>(x, label, adj, cw, cb, Vp, lw, Wb);
    gemm_bt<<<dim3(256), 512, 0, stream>>>(Vp, Wb, lb, out);
}

// Round 7
// 265.978 us; speedup vs baseline: 1.0299x; 1.0046x over previous
//
#include <hip/hip_runtime.h>

typedef __bf16 bf16;
typedef bf16 bf16x8 __attribute__((ext_vector_type(8)));
typedef float f32x4 __attribute__((ext_vector_type(4)));
typedef unsigned short ushort;
typedef ushort ushort4v __attribute__((ext_vector_type(4)));

#define BB 8192   // batch
#define NN 2048   // nodes

// ---------------------------------------------------------------------------
__device__ __forceinline__ void async16(const void* g, void* l) {
    __builtin_amdgcn_global_load_lds(
        (__attribute__((address_space(1))) void*)(void*)g,
        (__attribute__((address_space(3))) void*)l,
        16, 0, 0);
}

// ---------------------------------------------------------------------------
// K1 v5 (unchanged from R6): gather-conv writing the TRANSPOSED batch-8-
// grouped layout V'[g][p][e] = conv(batch g*8+e, node p).
// A[m][k0..k0+8) = V'[(m&3)*256 + k0/8][m>>2][0..8) -> 16B-contiguous chunks.
// Blocks >= 1024 do the lin_w f32->bf16 convert.
__global__ __launch_bounds__(256) void conv_gather_t(
    const float* __restrict__ x, const float* __restrict__ label,
    const int* __restrict__ adj, const float* __restrict__ cw,
    const float* __restrict__ cb, bf16* __restrict__ Vp,
    const float* __restrict__ W, bf16* __restrict__ Wb) {
    const int blk = blockIdx.x;
    const int t   = threadIdx.x;

    if (blk >= 1024) {
        const size_t f4 = ((size_t)(blk - 1024) * 256 + t) * 4;
        const float4* Wf = (const float4*)W;
        float4 v0 = Wf[f4 + 0], v1 = Wf[f4 + 1];
        float4 v2 = Wf[f4 + 2], v3 = Wf[f4 + 3];
        bf16x8 o0, o1;
        o0[0]=(bf16)v0.x; o0[1]=(bf16)v0.y; o0[2]=(bf16)v0.z; o0[3]=(bf16)v0.w;
        o0[4]=(bf16)v1.x; o0[5]=(bf16)v1.y; o0[6]=(bf16)v1.z; o0[7]=(bf16)v1.w;
        o1[0]=(bf16)v2.x; o1[1]=(bf16)v2.y; o1[2]=(bf16)v2.z; o1[3]=(bf16)v2.w;
        o1[4]=(bf16)v3.x; o1[5]=(bf16)v3.y; o1[6]=(bf16)v3.z; o1[7]=(bf16)v3.w;
        ((bf16x8*)Wb)[(f4 >> 1) + 0] = o0;
        ((bf16x8*)Wb)[(f4 >> 1) + 1] = o1;
        return;
    }

    __shared__ bf16x8 sxl[NN];   // 32 KB
    const int bb0 = blk * 8;

    const float w0 = cw[0], w1 = cw[1], w2 = cw[2], w3 = cw[3];
    const float w4 = cw[4], w5 = cw[5], w6 = cw[6], w7 = cw[7];
    const float bias = cb[0];

    const int4* adj4 = (const int4*)adj;
    int4 a[8];
#pragma unroll
    for (int j = 0; j < 8; ++j) a[j] = adj4[t * 8 + j];

    bf16 oA[8][4], oB[8][4];

#pragma unroll
    for (int pp = 0; pp < 2; ++pp) {
        if (pp) __syncthreads();   // protect pass-0 reads from restage
        const int rb = bb0 + pp * 4;
        const float4* x0 = (const float4*)(x     + (size_t)(rb + 0) * NN);
        const float4* x1 = (const float4*)(x     + (size_t)(rb + 1) * NN);
        const float4* x2 = (const float4*)(x     + (size_t)(rb + 2) * NN);
        const float4* x3 = (const float4*)(x     + (size_t)(rb + 3) * NN);
        const float4* l0 = (const float4*)(label + (size_t)(rb + 0) * NN);
        const float4* l1 = (const float4*)(label + (size_t)(rb + 1) * NN);
        const float4* l2 = (const float4*)(label + (size_t)(rb + 2) * NN);
        const float4* l3 = (const float4*)(label + (size_t)(rb + 3) * NN);
#pragma unroll
        for (int q = 0; q < 2; ++q) {
            int i = q * 256 + t;             // float4 index, 512 per row
            float4 xa = x0[i], xb = x1[i], xc = x2[i], xd = x3[i];
            float4 la = l0[i], lb = l1[i], lc = l2[i], ld = l3[i];
            int n0i = i * 4;
            int sx  = (i >> 1) & 7;          // == ((n0i+c)>>3)&7 for c=0..3
            bf16x8 e;
            e[0]=(bf16)xa.x; e[1]=(bf16)la.x; e[2]=(bf16)xb.x; e[3]=(bf16)lb.x;
            e[4]=(bf16)xc.x; e[5]=(bf16)lc.x; e[6]=(bf16)xd.x; e[7]=(bf16)ld.x;
            sxl[(n0i + 0) ^ sx] = e;
            e[0]=(bf16)xa.y; e[1]=(bf16)la.y; e[2]=(bf16)xb.y; e[3]=(bf16)lb.y;
            e[4]=(bf16)xc.y; e[5]=(bf16)lc.y; e[6]=(bf16)xd.y; e[7]=(bf16)ld.y;
            sxl[(n0i + 1) ^ sx] = e;
            e[0]=(bf16)xa.z; e[1]=(bf16)la.z; e[2]=(bf16)xb.z; e[3]=(bf16)lb.z;
            e[4]=(bf16)xc.z; e[5]=(bf16)lc.z; e[6]=(bf16)xd.z; e[7]=(bf16)ld.z;
            sxl[(n0i + 2) ^ sx] = e;
            e[0]=(bf16)xa.w; e[1]=(bf16)la.w; e[2]=(bf16)xb.w; e[3]=(bf16)lb.w;
            e[4]=(bf16)xc.w; e[5]=(bf16)lc.w; e[6]=(bf16)xd.w; e[7]=(bf16)ld.w;
            sxl[(n0i + 3) ^ sx] = e;
        }
        __syncthreads();

        bf16 (*od)[4] = pp ? oB : oA;
#pragma unroll
        for (int j = 0; j < 8; ++j) {
            int4 aa = a[j];
            bf16x8 p0 = sxl[aa.x ^ ((aa.x >> 3) & 7)];
            bf16x8 p1 = sxl[aa.y ^ ((aa.y >> 3) & 7)];
            bf16x8 p2 = sxl[aa.z ^ ((aa.z >> 3) & 7)];
            bf16x8 p3 = sxl[aa.w ^ ((aa.w >> 3) & 7)];
            float v0 = bias
                + w0*(float)p0[0] + w1*(float)p1[0] + w2*(float)p2[0] + w3*(float)p3[0]
                + w4*(float)p0[1] + w5*(float)p1[1] + w6*(float)p2[1] + w7*(float)p3[1];
            float v1 = bias
                + w0*(float)p0[2] + w1*(float)p1[2] + w2*(float)p2[2] + w3*(float)p3[2]
                + w4*(float)p0[3] + w5*(float)p1[3] + w6*(float)p2[3] + w7*(float)p3[3];
            float v2 = bias
                + w0*(float)p0[4] + w1*(float)p1[4] + w2*(float)p2[4] + w3*(float)p3[4]
                + w4*(float)p0[5] + w5*(float)p1[5] + w6*(float)p2[5] + w7*(float)p3[5];
            float v3 = bias
                + w0*(float)p0[6] + w1*(float)p1[6] + w2*(float)p2[6] + w3*(float)p3[6]
                + w4*(float)p0[7] + w5*(float)p1[7] + w6*(float)p2[7] + w7*(float)p3[7];
            od[j][0] = (bf16)fmaxf(v0, 0.0f);
            od[j][1] = (bf16)fmaxf(v1, 0.0f);
            od[j][2] = (bf16)fmaxf(v2, 0.0f);
            od[j][3] = (bf16)fmaxf(v3, 0.0f);
        }
    }

    bf16* vout = Vp + (size_t)blk * 16384 + t * 64;
#pragma unroll
    for (int j = 0; j < 8; ++j) {
        bf16x8 e;
        e[0] = oA[j][0]; e[1] = oA[j][1]; e[2] = oA[j][2]; e[3] = oA[j][3];
        e[4] = oB[j][0]; e[5] = oB[j][1]; e[6] = oB[j][2]; e[7] = oB[j][3];
        *(bf16x8*)(vout + j * 8) = e;
    }
}

// ---------------------------------------------------------------------------
// K3: out(8192x2048) = A * W^T + bias.  R3 schedule + ledger (unchanged).
// R7 change: the A-side LDS layout is a bijective 16B-chunk permutation of
// the 128x64 half-tile, co-designed for V' (fixes the R6 regression where
// per-wave A-fetches degenerated to 32 scattered 32B chunks):
//   chunk'(sg,p) = s4*512 | slot*64 | p*2 | s3
//   where sg = (m&3)*8+slot (slot = k>>3 in [0,8)), p = m>>2 (in [0,32)),
//   s4s3 = m&3 bits, element off = chunk'*8 + (k&7).
// Properties (derived, see round notes):
//  * global fetch: wave w / async j reads mg=2j+(lane&1), slot=w, p=lane>>1
//    -> TWO contiguous 512B runs per async16 per wave (R6: 32x32B scatter).
//  * ds_read banks: frag byte-in-128B = 32*(l16>>2)+16*(l16&1) -> all 8
//    16B slots covered, 2-way aliasing (the measured-zero class).
//  * LDS dest stays linear (lane*16), per rule #21: permute SOURCE + READ.
// B-side staging/reads and the 8-phase vmcnt(6) ledger are untouched.
__global__ __launch_bounds__(512, 2) void gemm_bt(
    const bf16* __restrict__ A, const bf16* __restrict__ W,
    const float* __restrict__ bias, float* __restrict__ out) {
    __shared__ __attribute__((aligned(16))) bf16 sA[2][16384];
    __shared__ __attribute__((aligned(16))) bf16 sB[2][16384];

    const int t    = threadIdx.x;
    const int lane = t & 63;
    const int wv   = t >> 6;
    const int wm   = wv & 1;     // 2 M-waves
    const int wn   = wv >> 1;    // 4 N-waves
    const int l16  = lane & 15;
    const int l4   = lane >> 4;

    // Chunked XCD mapping: each XCD owns 4 bx (A panels) x all 8 by.
    const int xcd = blockIdx.x & 7;
    const int loc = blockIdx.x >> 3;        // [0,32)
    const int bx  = xcd * 4 + (loc >> 3);   // [0,32)
    const int by  = loc & 7;                // [0,8)
    const int m0  = bx * 256;
    const int n0  = by * 256;

    // B staging thread map (unchanged)
    const int r8  = t >> 3;
    const int c8  = ((t & 7) ^ (r8 & 7)) * 8;
    const int dst = t * 8;

    // A staging source decode: chunk c = j*512 + t ->
    //   s3 = c&1, p = (c>>1)&31, slot = (c>>6)&7, s4 = (c>>9)&1
    //   src elem = (mg*256 + kt/8 + slot)*16384 + (rb/4 + p)*8
    //            = mg*4194304 + slot*16384 + p*8  +  kt*2048 + rb*2
    int aBv[2];
#pragma unroll
    for (int j = 0; j < 2; ++j) {
        const int c  = j * 512 + t;
        const int s3 = c & 1, pC = (c >> 1) & 31;
        const int sl = (c >> 6) & 7, s4 = (c >> 9) & 1;
        aBv[j] = (s4 * 2 + s3) * 4194304 + sl * 16384 + pC * 8;
    }
    const int aBase0 = aBv[0], aBase1 = aBv[1];

    // A frag read offsets: off = wm*8192 + mh*256 + i*64 + ks*2048 + aC
    //   aC = s4(l16)*4096 + (l16>>2)*16 + (l16&1)*8 + l4*512
    const int aC = ((l16 >> 1) & 1) * 4096 + (l16 >> 2) * 16 + (l16 & 1) * 8
                 + l4 * 512;

    // B frag read offsets (unchanged)
    const int sw    = l16 & 7;
    const int bOff0 = (wn * 64 + l16) * 64 + ((l4    ) ^ sw) * 8;
    const int bOff1 = (wn * 64 + l16) * 64 + ((l4 + 4) ^ sw) * 8;

    f32x4  acc[8][4] = {};
    bf16x8 aR[4][2], bR[4][2];

#define GBAR()  asm volatile("s_barrier" ::: "memory")
#define LGKM0() do { asm volatile("s_waitcnt lgkmcnt(0)" ::: "memory"); \
                     __builtin_amdgcn_sched_barrier(0); } while (0)
#define VMW6()  asm volatile("s_waitcnt vmcnt(6)" ::: "memory")
#define VMW0()  asm volatile("s_waitcnt vmcnt(0)" ::: "memory")

// B (W) staging: row-major [n][k] (unchanged)
#define STGW(rb, kt, lp) do {                                             \
        const bf16* _s = W + (size_t)((rb) + r8) * 2048 + (kt) + c8;      \
        async16(_s, (lp) + dst);                                          \
        async16(_s + (size_t)64 * 2048, (lp) + 4096 + dst);               \
    } while (0)

// A staging from V' via the chunk' bijection: 2x512B runs per wave/async.
#define STGA(rb, kt, lp) do {                                             \
        const size_t _o = (size_t)(kt) * 2048 + (rb) * 2;                 \
        async16(A + aBase0 + _o, (lp) + dst);                             \
        async16(A + aBase1 + _o, (lp) + 4096 + dst);                      \
    } while (0)

// A frag reads in the chunk' layout
#define LDA(sp, mh) do {                                                  \
        const bf16* _p = (sp) + wm * 8192 + (mh) * 256 + aC;              \
        aR[0][0] = *(const bf16x8*)(_p +   0);                            \
        aR[0][1] = *(const bf16x8*)(_p +   0 + 2048);                     \
        aR[1][0] = *(const bf16x8*)(_p +  64);                            \
        aR[1][1] = *(const bf16x8*)(_p +  64 + 2048);                     \
        aR[2][0] = *(const bf16x8*)(_p + 128);                            \
        aR[2][1] = *(const bf16x8*)(_p + 128 + 2048);                     \
        aR[3][0] = *(const bf16x8*)(_p + 192);                            \
        aR[3][1] = *(const bf16x8*)(_p + 192 + 2048);                     \
    } while (0)

#define LDB(sp, nh) do {                                                  \
        const bf16* _p = (sp) + (nh) * 2048;                              \
        bR[(nh)*2+0][0] = *(const bf16x8*)(_p + bOff0);                   \
        bR[(nh)*2+0][1] = *(const bf16x8*)(_p + bOff1);                   \
        bR[(nh)*2+1][0] = *(const bf16x8*)(_p + 1024 + bOff0);            \
        bR[(nh)*2+1][1] = *(const bf16x8*)(_p + 1024 + bOff1);            \
    } while (0)

#define MM(mh, nh) do {                                                   \
        __builtin_amdgcn_s_setprio(1);                                    \
        _Pragma("unroll")                                                 \
        for (int _ks = 0; _ks < 2; ++_ks)                                 \
            _Pragma("unroll")                                             \
            for (int _mf = 0; _mf < 4; ++_mf)                             \
                _Pragma("unroll")                                         \
                for (int _nf = 0; _nf < 2; ++_nf)                         \
                    acc[(mh)*4+_mf][(nh)*2+_nf] =                         \
                        __builtin_amdgcn_mfma_f32_16x16x32_bf16(          \
                            aR[_mf][_ks], bR[(nh)*2+_nf][_ks],            \
                            acc[(mh)*4+_mf][(nh)*2+_nf], 0, 0, 0);        \
        __builtin_amdgcn_s_setprio(0);                                    \
    } while (0)

    bf16* const sA0 = &sA[0][0]; bf16* const sA1 = &sA[1][0];
    bf16* const sB0 = &sB[0][0]; bf16* const sB1 = &sB[1][0];

    // prologue: A(0),B(0) (8 ops) + B(1),A(1).h0 (6 ops) = 14; vmcnt(6)
    // retires the 8 oldest = all of tile 0, leaving invariant
    // {B(1).h0, B(1).h1, A(1).h0}.
    STGA(m0,       0,  sA0);
    STGA(m0 + 128, 0,  sA0 + 8192);
    STGW(n0,       0,  sB0);
    STGW(n0 + 128, 0,  sB0 + 8192);
    STGW(n0,       64, sB1);
    STGW(n0 + 128, 64, sB1 + 8192);
    STGA(m0,       64, sA1);
    VMW6();
    GBAR();

    for (int i = 0; i < 15; ++i) {
        const int kb = i * 128;
        // ph1: stage A(2i+1).h1
        LDA(sA0, 0); LDB(sB0, 0);
        STGA(m0 + 128, kb + 64, sA1 + 8192);
        GBAR(); LGKM0();
        MM(0, 0);
        GBAR();
        // ph2
        LDB(sB0, 1);
        GBAR(); LGKM0();
        MM(0, 1);
        GBAR();
        // ph3: stage B(2i+2).h0
        LDA(sA0, 1);
        STGW(n0, kb + 128, sB0);
        GBAR(); LGKM0();
        MM(1, 0);
        GBAR();
        // ph4: stage B(2i+2).h1 + A(2i+2).h0; wait buf1
        STGW(n0 + 128, kb + 128, sB0 + 8192);
        STGA(m0,       kb + 128, sA0);
        GBAR(); LGKM0();
        MM(1, 1);
        VMW6();
        GBAR();
        // ph5: stage A(2i+2).h1
        LDA(sA1, 0); LDB(sB1, 0);
        STGA(m0 + 128, kb + 128, sA0 + 8192);
        GBAR(); LGKM0();
        MM(0, 0);
        GBAR();
        // ph6
        LDB(sB1, 1);
        GBAR(); LGKM0();
        MM(0, 1);
        GBAR();
        // ph7: stage B(2i+3).h0
        LDA(sA1, 1);
        STGW(n0, kb + 192, sB1);
        GBAR(); LGKM0();
        MM(1, 0);
        GBAR();
        // ph8: stage B(2i+3).h1 + A(2i+3).h0; wait buf0
        STGW(n0 + 128, kb + 192, sB1 + 8192);
        STGA(m0,       kb + 192, sA1);
        GBAR(); LGKM0();
        MM(1, 1);
        VMW6();
        GBAR();
    }

    // tail: tiles 30 (buf0), 31 (buf1); only A(31).h1 remains to stage
    LDA(sA0, 0); LDB(sB0, 0);
    STGA(m0 + 128, 1984, sA1 + 8192);
    GBAR(); LGKM0(); MM(0, 0); GBAR();
    LDB(sB0, 1);
    GBAR(); LGKM0(); MM(0, 1); GBAR();
    LDA(sA0, 1);
    GBAR(); LGKM0(); MM(1, 0); GBAR();
    GBAR(); LGKM0(); MM(1, 1);
    VMW0();                      // drain tile 31
    GBAR();
    LDA(sA1, 0); LDB(sB1, 0);
    GBAR(); LGKM0(); MM(0, 0); GBAR();
    LDB(sB1, 1);
    GBAR(); LGKM0(); MM(0, 1); GBAR();
    LDA(sA1, 1);
    GBAR(); LGKM0(); MM(1, 0); GBAR();
    GBAR(); LGKM0(); MM(1, 1);

    // epilogue: bias + store (regs only)
#pragma unroll
    for (int nf = 0; nf < 4; ++nf) {
        const int col = n0 + wn * 64 + nf * 16 + l16;
        const float bc = bias[col];
#pragma unroll
        for (int mf = 0; mf < 8; ++mf) {
            const size_t row = (size_t)(m0 + wm * 128 + mf * 16 + l4 * 4);
#pragma unroll
            for (int rr = 0; rr < 4; ++rr)
                out[(row + rr) * 2048 + col] = acc[mf][nf][rr] + bc;
        }
    }
#undef STGW
#undef STGA
#undef LDA
#undef LDB
#undef MM
#undef GBAR
#undef LGKM0
#undef VMW6
#undef VMW0
}

// ---------------------------------------------------------------------------
extern "C" void kernel_launch(void* const* d_in, const int* in_sizes, int n_in,
                              void* d_out, int out_size, void* d_ws, size_t ws_size,
                              hipStream_t stream) {
    (void)in_sizes; (void)n_in; (void)out_size; (void)ws_size;
    const float* x     = (const float*)d_in[0];
    const float* label = (const float*)d_in[1];
    const int*   adj   = (const int*)d_in[2];
    const float* cw    = (const float*)d_in[3];
    const float* cb    = (const float*)d_in[4];
    const float* lw    = (const float*)d_in[5];
    const float* lb    = (const float*)d_in[6];
    float* out = (float*)d_out;

    // scratch: V' (33.5 MB) at ws, Wb at ws+33.5MB.
    bf16* Vp = (bf16*)d_ws;
    bf16* Wb = (bf16*)((char*)d_ws + (size_t)2048 * 8192 * 2);

    conv_gather_t<<<2048, 256, 0, stream>>>(x, label, adj, cw, cb, Vp, lw, Wb);
    gemm_bt<<<dim3(256), 512, 0, stream>>>(Vp, Wb, lb, out);
}

// Round 8
// 265.876 us; speedup vs baseline: 1.0303x; 1.0004x over previous
//
#include <hip/hip_runtime.h>

typedef __bf16 bf16;
typedef bf16 bf16x8 __attribute__((ext_vector_type(8)));
typedef float f32x4 __attribute__((ext_vector_type(4)));
typedef unsigned short ushort;
typedef ushort ushort4v __attribute__((ext_vector_type(4)));

#define BB 8192   // batch
#define NN 2048   // nodes

// ---------------------------------------------------------------------------
__device__ __forceinline__ void async16(const void* g, void* l) {
    __builtin_amdgcn_global_load_lds(
        (__attribute__((address_space(1))) void*)(void*)g,
        (__attribute__((address_space(3))) void*)l,
        16, 0, 0);
}

// ---------------------------------------------------------------------------
// K1 v5 (unchanged): gather-conv writing the TRANSPOSED batch-8-grouped
// layout V'[g][p][e] = conv(batch g*8+e, node p).
// A[m][k0..k0+8) = V'[(m&3)*256 + k0/8][m>>2][0..8) -> 16B-contiguous chunks.
// Blocks >= 1024 do the lin_w f32->bf16 convert.
__global__ __launch_bounds__(256) void conv_gather_t(
    const float* __restrict__ x, const float* __restrict__ label,
    const int* __restrict__ adj, const float* __restrict__ cw,
    const float* __restrict__ cb, bf16* __restrict__ Vp,
    const float* __restrict__ W, bf16* __restrict__ Wb) {
    const int blk = blockIdx.x;
    const int t   = threadIdx.x;

    if (blk >= 1024) {
        const size_t f4 = ((size_t)(blk - 1024) * 256 + t) * 4;
        const float4* Wf = (const float4*)W;
        float4 v0 = Wf[f4 + 0], v1 = Wf[f4 + 1];
        float4 v2 = Wf[f4 + 2], v3 = Wf[f4 + 3];
        bf16x8 o0, o1;
        o0[0]=(bf16)v0.x; o0[1]=(bf16)v0.y; o0[2]=(bf16)v0.z; o0[3]=(bf16)v0.w;
        o0[4]=(bf16)v1.x; o0[5]=(bf16)v1.y; o0[6]=(bf16)v1.z; o0[7]=(bf16)v1.w;
        o1[0]=(bf16)v2.x; o1[1]=(bf16)v2.y; o1[2]=(bf16)v2.z; o1[3]=(bf16)v2.w;
        o1[4]=(bf16)v3.x; o1[5]=(bf16)v3.y; o1[6]=(bf16)v3.z; o1[7]=(bf16)v3.w;
        ((bf16x8*)Wb)[(f4 >> 1) + 0] = o0;
        ((bf16x8*)Wb)[(f4 >> 1) + 1] = o1;
        return;
    }

    __shared__ bf16x8 sxl[NN];   // 32 KB
    const int bb0 = blk * 8;

    const float w0 = cw[0], w1 = cw[1], w2 = cw[2], w3 = cw[3];
    const float w4 = cw[4], w5 = cw[5], w6 = cw[6], w7 = cw[7];
    const float bias = cb[0];

    const int4* adj4 = (const int4*)adj;
    int4 a[8];
#pragma unroll
    for (int j = 0; j < 8; ++j) a[j] = adj4[t * 8 + j];

    bf16 oA[8][4], oB[8][4];

#pragma unroll
    for (int pp = 0; pp < 2; ++pp) {
        if (pp) __syncthreads();   // protect pass-0 reads from restage
        const int rb = bb0 + pp * 4;
        const float4* x0 = (const float4*)(x     + (size_t)(rb + 0) * NN);
        const float4* x1 = (const float4*)(x     + (size_t)(rb + 1) * NN);
        const float4* x2 = (const float4*)(x     + (size_t)(rb + 2) * NN);
        const float4* x3 = (const float4*)(x     + (size_t)(rb + 3) * NN);
        const float4* l0 = (const float4*)(label + (size_t)(rb + 0) * NN);
        const float4* l1 = (const float4*)(label + (size_t)(rb + 1) * NN);
        const float4* l2 = (const float4*)(label + (size_t)(rb + 2) * NN);
        const float4* l3 = (const float4*)(label + (size_t)(rb + 3) * NN);
#pragma unroll
        for (int q = 0; q < 2; ++q) {
            int i = q * 256 + t;             // float4 index, 512 per row
            float4 xa = x0[i], xb = x1[i], xc = x2[i], xd = x3[i];
            float4 la = l0[i], lb = l1[i], lc = l2[i], ld = l3[i];
            int n0i = i * 4;
            int sx  = (i >> 1) & 7;          // == ((n0i+c)>>3)&7 for c=0..3
            bf16x8 e;
            e[0]=(bf16)xa.x; e[1]=(bf16)la.x; e[2]=(bf16)xb.x; e[3]=(bf16)lb.x;
            e[4]=(bf16)xc.x; e[5]=(bf16)lc.x; e[6]=(bf16)xd.x; e[7]=(bf16)ld.x;
            sxl[(n0i + 0) ^ sx] = e;
            e[0]=(bf16)xa.y; e[1]=(bf16)la.y; e[2]=(bf16)xb.y; e[3]=(bf16)lb.y;
            e[4]=(bf16)xc.y; e[5]=(bf16)lc.y; e[6]=(bf16)xd.y; e[7]=(bf16)ld.y;
            sxl[(n0i + 1) ^ sx] = e;
            e[0]=(bf16)xa.z; e[1]=(bf16)la.z; e[2]=(bf16)xb.z; e[3]=(bf16)lb.z;
            e[4]=(bf16)xc.z; e[5]=(bf16)lc.z; e[6]=(bf16)xd.z; e[7]=(bf16)ld.z;
            sxl[(n0i + 2) ^ sx] = e;
            e[0]=(bf16)xa.w; e[1]=(bf16)la.w; e[2]=(bf16)xb.w; e[3]=(bf16)lb.w;
            e[4]=(bf16)xc.w; e[5]=(bf16)lc.w; e[6]=(bf16)xd.w; e[7]=(bf16)ld.w;
            sxl[(n0i + 3) ^ sx] = e;
        }
        __syncthreads();

        bf16 (*od)[4] = pp ? oB : oA;
#pragma unroll
        for (int j = 0; j < 8; ++j) {
            int4 aa = a[j];
            bf16x8 p0 = sxl[aa.x ^ ((aa.x >> 3) & 7)];
            bf16x8 p1 = sxl[aa.y ^ ((aa.y >> 3) & 7)];
            bf16x8 p2 = sxl[aa.z ^ ((aa.z >> 3) & 7)];
            bf16x8 p3 = sxl[aa.w ^ ((aa.w >> 3) & 7)];
            float v0 = bias
                + w0*(float)p0[0] + w1*(float)p1[0] + w2*(float)p2[0] + w3*(float)p3[0]
                + w4*(float)p0[1] + w5*(float)p1[1] + w6*(float)p2[1] + w7*(float)p3[1];
            float v1 = bias
                + w0*(float)p0[2] + w1*(float)p1[2] + w2*(float)p2[2] + w3*(float)p3[2]
                + w4*(float)p0[3] + w5*(float)p1[3] + w6*(float)p2[3] + w7*(float)p3[3];
            float v2 = bias
                + w0*(float)p0[4] + w1*(float)p1[4] + w2*(float)p2[4] + w3*(float)p3[4]
                + w4*(float)p0[5] + w5*(float)p1[5] + w6*(float)p2[5] + w7*(float)p3[5];
            float v3 = bias
                + w0*(float)p0[6] + w1*(float)p1[6] + w2*(float)p2[6] + w3*(float)p3[6]
                + w4*(float)p0[7] + w5*(float)p1[7] + w6*(float)p2[7] + w7*(float)p3[7];
            od[j][0] = (bf16)fmaxf(v0, 0.0f);
            od[j][1] = (bf16)fmaxf(v1, 0.0f);
            od[j][2] = (bf16)fmaxf(v2, 0.0f);
            od[j][3] = (bf16)fmaxf(v3, 0.0f);
        }
    }

    bf16* vout = Vp + (size_t)blk * 16384 + t * 64;
#pragma unroll
    for (int j = 0; j < 8; ++j) {
        bf16x8 e;
        e[0] = oA[j][0]; e[1] = oA[j][1]; e[2] = oA[j][2]; e[3] = oA[j][3];
        e[4] = oB[j][0]; e[5] = oB[j][1]; e[6] = oB[j][2]; e[7] = oB[j][3];
        *(bf16x8*)(vout + j * 8) = e;
    }
}

// ---------------------------------------------------------------------------
// K3: out(8192x2048) = A * W^T + bias.  R3 schedule + ledger (unchanged).
// R8 change vs R7: bank-fix XOR on the A-side chunk permutation.
//   chunk ↦ chunk ^ ((chunk>>6)&7)   (self-inverse; low-3 bits XOR'd by a
//   value independent of low-3 bits -> bijective per 64-chunk group)
// Why: R3/R6's verified-zero A-read pattern has bank-group = l4 ^ (l16&7)
// (l4-DEPENDENT); R7's conflicted pattern had bank indep of l4. The XOR
// makes the read bank-group (q*2+s3) ^ (ks*4+l4) -> l4-dependent (R3 class).
// Coalescing preserved: each async16's 64 chunks are one 64-aligned group
// (c = j*512 + w*64 + lane), so (c>>6)&7 is wave-uniform -> the XOR only
// permutes lanes within the same source-address set (still 2x512B runs).
// Stage/read XORs cancel: src(l ^ x ^ x) = src(l).
__global__ __launch_bounds__(512, 2) void gemm_bt(
    const bf16* __restrict__ A, const bf16* __restrict__ W,
    const float* __restrict__ bias, float* __restrict__ out) {
    __shared__ __attribute__((aligned(16))) bf16 sA[2][16384];
    __shared__ __attribute__((aligned(16))) bf16 sB[2][16384];

    const int t    = threadIdx.x;
    const int lane = t & 63;
    const int wv   = t >> 6;
    const int wm   = wv & 1;     // 2 M-waves
    const int wn   = wv >> 1;    // 4 N-waves
    const int l16  = lane & 15;
    const int l4   = lane >> 4;

    // Chunked XCD mapping: each XCD owns 4 bx (A panels) x all 8 by.
    const int xcd = blockIdx.x & 7;
    const int loc = blockIdx.x >> 3;        // [0,32)
    const int bx  = xcd * 4 + (loc >> 3);   // [0,32)
    const int by  = loc & 7;                // [0,8)
    const int m0  = bx * 256;
    const int n0  = by * 256;

    // B staging thread map (unchanged)
    const int r8  = t >> 3;
    const int c8  = ((t & 7) ^ (r8 & 7)) * 8;
    const int dst = t * 8;

    // A staging source decode WITH bank-fix XOR: LDS chunk c holds source
    // chunk cd = c ^ ((c>>6)&7); decode cd as in R7:
    //   s3 = cd&1, p = (cd>>1)&31, slot = (cd>>6)&7, s4 = (cd>>9)&1
    //   src elem = (s4*2+s3)*4194304 + slot*16384 + p*8  (+ kt*2048 + rb*2)
    int aBv[2];
#pragma unroll
    for (int j = 0; j < 2; ++j) {
        const int c  = j * 512 + t;
        const int cd = c ^ ((c >> 6) & 7);
        const int s3 = cd & 1, pC = (cd >> 1) & 31;
        const int sl = (cd >> 6) & 7, s4 = (cd >> 9) & 1;
        aBv[j] = (s4 * 2 + s3) * 4194304 + sl * 16384 + pC * 8;
    }
    const int aBase0 = aBv[0], aBase1 = aBv[1];

    // A frag read offsets with the same XOR applied:
    //   logical low-3 chunk bits bq = (l16>>2)*2 + (l16&1); XOR by (ks*4+l4)
    //   read elem = wm*8192 + ks*2048 + s4*4096 + l4*512 + (bq^(ks*4+l4))*8
    //              + mh*256 + i*64
    {
    }
    const int qv  = l16 >> 2;
    const int s3r = l16 & 1;
    const int s4r = (l16 >> 1) & 1;
    const int bq  = qv * 2 + s3r;
    const int aOffX0 = wm * 8192 + s4r * 4096 + l4 * 512 + ((bq ^ l4) * 8);
    const int aOffX1 = wm * 8192 + 2048 + s4r * 4096 + l4 * 512
                     + ((bq ^ (4 + l4)) * 8);

    // B frag read offsets (unchanged)
    const int sw    = l16 & 7;
    const int bOff0 = (wn * 64 + l16) * 64 + ((l4    ) ^ sw) * 8;
    const int bOff1 = (wn * 64 + l16) * 64 + ((l4 + 4) ^ sw) * 8;

    f32x4  acc[8][4] = {};
    bf16x8 aR[4][2], bR[4][2];

#define GBAR()  asm volatile("s_barrier" ::: "memory")
#define LGKM0() do { asm volatile("s_waitcnt lgkmcnt(0)" ::: "memory"); \
                     __builtin_amdgcn_sched_barrier(0); } while (0)
#define VMW6()  asm volatile("s_waitcnt vmcnt(6)" ::: "memory")
#define VMW0()  asm volatile("s_waitcnt vmcnt(0)" ::: "memory")

// B (W) staging: row-major [n][k] (unchanged)
#define STGW(rb, kt, lp) do {                                             \
        const bf16* _s = W + (size_t)((rb) + r8) * 2048 + (kt) + c8;      \
        async16(_s, (lp) + dst);                                          \
        async16(_s + (size_t)64 * 2048, (lp) + 4096 + dst);               \
    } while (0)

// A staging from V' via the XOR'd chunk bijection: 2x512B runs per async.
#define STGA(rb, kt, lp) do {                                             \
        const size_t _o = (size_t)(kt) * 2048 + (rb) * 2;                 \
        async16(A + aBase0 + _o, (lp) + dst);                             \
        async16(A + aBase1 + _o, (lp) + 4096 + dst);                      \
    } while (0)

// A frag reads in the XOR'd chunk layout
#define LDA(sp, mh) do {                                                  \
        const bf16* _p = (sp) + (mh) * 256;                               \
        aR[0][0] = *(const bf16x8*)(_p +   0 + aOffX0);                   \
        aR[0][1] = *(const bf16x8*)(_p +   0 + aOffX1);                   \
        aR[1][0] = *(const bf16x8*)(_p +  64 + aOffX0);                   \
        aR[1][1] = *(const bf16x8*)(_p +  64 + aOffX1);                   \
        aR[2][0] = *(const bf16x8*)(_p + 128 + aOffX0);                   \
        aR[2][1] = *(const bf16x8*)(_p + 128 + aOffX1);                   \
        aR[3][0] = *(const bf16x8*)(_p + 192 + aOffX0);                   \
        aR[3][1] = *(const bf16x8*)(_p + 192 + aOffX1);                   \
    } while (0)

#define LDB(sp, nh) do {                                                  \
        const bf16* _p = (sp) + (nh) * 2048;                              \
        bR[(nh)*2+0][0] = *(const bf16x8*)(_p + bOff0);                   \
        bR[(nh)*2+0][1] = *(const bf16x8*)(_p + bOff1);                   \
        bR[(nh)*2+1][0] = *(const bf16x8*)(_p + 1024 + bOff0);            \
        bR[(nh)*2+1][1] = *(const bf16x8*)(_p + 1024 + bOff1);            \
    } while (0)

#define MM(mh, nh) do {                                                   \
        __builtin_amdgcn_s_setprio(1);                                    \
        _Pragma("unroll")                                                 \
        for (int _ks = 0; _ks < 2; ++_ks)                                 \
            _Pragma("unroll")                                             \
            for (int _mf = 0; _mf < 4; ++_mf)                             \
                _Pragma("unroll")                                         \
                for (int _nf = 0; _nf < 2; ++_nf)                         \
                    acc[(mh)*4+_mf][(nh)*2+_nf] =                         \
                        __builtin_amdgcn_mfma_f32_16x16x32_bf16(          \
                            aR[_mf][_ks], bR[(nh)*2+_nf][_ks],            \
                            acc[(mh)*4+_mf][(nh)*2+_nf], 0, 0, 0);        \
        __builtin_amdgcn_s_setprio(0);                                    \
    } while (0)

    bf16* const sA0 = &sA[0][0]; bf16* const sA1 = &sA[1][0];
    bf16* const sB0 = &sB[0][0]; bf16* const sB1 = &sB[1][0];

    // prologue: A(0),B(0) (8 ops) + B(1),A(1).h0 (6 ops) = 14; vmcnt(6)
    // retires the 8 oldest = all of tile 0, leaving invariant
    // {B(1).h0, B(1).h1, A(1).h0}.
    STGA(m0,       0,  sA0);
    STGA(m0 + 128, 0,  sA0 + 8192);
    STGW(n0,       0,  sB0);
    STGW(n0 + 128, 0,  sB0 + 8192);
    STGW(n0,       64, sB1);
    STGW(n0 + 128, 64, sB1 + 8192);
    STGA(m0,       64, sA1);
    VMW6();
    GBAR();

    for (int i = 0; i < 15; ++i) {
        const int kb = i * 128;
        // ph1: stage A(2i+1).h1
        LDA(sA0, 0); LDB(sB0, 0);
        STGA(m0 + 128, kb + 64, sA1 + 8192);
        GBAR(); LGKM0();
        MM(0, 0);
        GBAR();
        // ph2
        LDB(sB0, 1);
        GBAR(); LGKM0();
        MM(0, 1);
        GBAR();
        // ph3: stage B(2i+2).h0
        LDA(sA0, 1);
        STGW(n0, kb + 128, sB0);
        GBAR(); LGKM0();
        MM(1, 0);
        GBAR();
        // ph4: stage B(2i+2).h1 + A(2i+2).h0; wait buf1
        STGW(n0 + 128, kb + 128, sB0 + 8192);
        STGA(m0,       kb + 128, sA0);
        GBAR(); LGKM0();
        MM(1, 1);
        VMW6();
        GBAR();
        // ph5: stage A(2i+2).h1
        LDA(sA1, 0); LDB(sB1, 0);
        STGA(m0 + 128, kb + 128, sA0 + 8192);
        GBAR(); LGKM0();
        MM(0, 0);
        GBAR();
        // ph6
        LDB(sB1, 1);
        GBAR(); LGKM0();
        MM(0, 1);
        GBAR();
        // ph7: stage B(2i+3).h0
        LDA(sA1, 1);
        STGW(n0, kb + 192, sB1);
        GBAR(); LGKM0();
        MM(1, 0);
        GBAR();
        // ph8: stage B(2i+3).h1 + A(2i+3).h0; wait buf0
        STGW(n0 + 128, kb + 192, sB1 + 8192);
        STGA(m0,       kb + 192, sA1);
        GBAR(); LGKM0();
        MM(1, 1);
        VMW6();
        GBAR();
    }

    // tail: tiles 30 (buf0), 31 (buf1); only A(31).h1 remains to stage
    LDA(sA0, 0); LDB(sB0, 0);
    STGA(m0 + 128, 1984, sA1 + 8192);
    GBAR(); LGKM0(); MM(0, 0); GBAR();
    LDB(sB0, 1);
    GBAR(); LGKM0(); MM(0, 1); GBAR();
    LDA(sA0, 1);
    GBAR(); LGKM0(); MM(1, 0); GBAR();
    GBAR(); LGKM0(); MM(1, 1);
    VMW0();                      // drain tile 31
    GBAR();
    LDA(sA1, 0); LDB(sB1, 0);
    GBAR(); LGKM0(); MM(0, 0); GBAR();
    LDB(sB1, 1);
    GBAR(); LGKM0(); MM(0, 1); GBAR();
    LDA(sA1, 1);
    GBAR(); LGKM0(); MM(1, 0); GBAR();
    GBAR(); LGKM0(); MM(1, 1);

    // epilogue: bias + store (regs only)
#pragma unroll
    for (int nf = 0; nf < 4; ++nf) {
        const int col = n0 + wn * 64 + nf * 16 + l16;
        const float bc = bias[col];
#pragma unroll
        for (int mf = 0; mf < 8; ++mf) {
            const size_t row = (size_t)(m0 + wm * 128 + mf * 16 + l4 * 4);
#pragma unroll
            for (int rr = 0; rr < 4; ++rr)
                out[(row + rr) * 2048 + col] = acc[mf][nf][rr] + bc;
        }
    }
#undef STGW
#undef STGA
#undef LDA
#undef LDB
#undef MM
#undef GBAR
#undef LGKM0
#undef VMW6
#undef VMW0
}

// ---------------------------------------------------------------------------
extern "C" void kernel_launch(void* const* d_in, const int* in_sizes, int n_in,
                              void* d_out, int out_size, void* d_ws, size_t ws_size,
                              hipStream_t stream) {
    (void)in_sizes; (void)n_in; (void)out_size; (void)ws_size;
    const float* x     = (const float*)d_in[0];
    const float* label = (const float*)d_in[1];
    const int*   adj   = (const int*)d_in[2];
    const float* cw    = (const float*)d_in[3];
    const float* cb    = (const float*)d_in[4];
    const float* lw    = (const float*)d_in[5];
    const float* lb    = (const float*)d_in[6];
    float* out = (float*)d_out;

    // scratch: V' (33.5 MB) at ws, Wb at ws+33.5MB.
    bf16* Vp = (bf16*)d_ws;
    bf16* Wb = (bf16*)((char*)d_ws + (size_t)2048 * 8192 * 2);

    conv_gather_t<<<2048, 256, 0, stream>>>(x, label, adj, cw, cb, Vp, lw, Wb);
    gemm_bt<<<dim3(256), 512, 0, stream>>>(Vp, Wb, lb, out);
}